// Round 2
// baseline (20934.482 us; speedup 1.0000x reference)
//
#include <hip/hip_runtime.h>
#include <cstdint>
#include <cstddef>

// SingleLayerLSTM: B=128, T=2048, D=64, H=256, O=32.
// v2: pair-split persistent kernel, row-split columns to kill the VGPR spill.
//  - 256 blocks x 1024 threads; block = (batch p = blk&127, half q = blk>>7).
//  - Thread = (channel c = tid>>3, gate g = (tid>>1)&3, row-half hh = tid&1).
//    Owns 160 of the 320 rows of one weight column as 80 fp16-pairs = 80 VGPRs
//    -> fits under the 128-VGPR cap of __launch_bounds__(1024,4); v1's 160-reg
//    array spilled to scratch (VGPR_Count=128, 10us/step of L3-hit reloads).
//  - [u_t | h_{t-1}] in LDS (fp16, parity double-buffered); matvec reads are
//    wave-uniform broadcast ds_read_b128.
//  - Partial combine: shfl_xor(1) sums row-halves; shfl_xor(2/4/6) swaps gates.
//  - Halves exchange h via parity-double-buffered L2 buffer + release/acquire
//    agent-scope flag (monotonic step; 0xAA poison is negative -> no init).
//  - y_{t-1} computed one step behind by q==0 blocks (32x32 partials + LDS reduce).

#define HH 256
#define DD 64
#define TT 2048
#define BB 128
#define OO 32
#define KR 320   // D + H rows
#define NPH 80   // fp16 pairs per thread (half a column)

typedef _Float16 f16x2 __attribute__((ext_vector_type(2)));

__device__ __forceinline__ f16x2 b2h(int v) { return __builtin_bit_cast(f16x2, v); }

#if __has_builtin(__builtin_amdgcn_fdot2)
__device__ __forceinline__ float fdot2(f16x2 a, f16x2 b, float c) {
  return __builtin_amdgcn_fdot2(a, b, c, false);
}
#else
__device__ __forceinline__ float fdot2(f16x2 a, f16x2 b, float c) {
  return fmaf((float)a.y, (float)b.y, fmaf((float)a.x, (float)b.x, c));
}
#endif

__device__ __forceinline__ float frcp(float x) { return __builtin_amdgcn_rcpf(x); }
__device__ __forceinline__ float sigm(float x)  { return frcp(1.0f + __expf(-x)); }
__device__ __forceinline__ float tanhf_(float x){ return 1.0f - 2.0f * frcp(1.0f + __expf(2.0f * x)); }

__global__ __launch_bounds__(1024, 4)
void lstm_persist(const float* __restrict__ u,    const float* __restrict__ x0,
                  const float* __restrict__ kfiz, const float* __restrict__ bfiz,
                  const float* __restrict__ kr,   const float* __restrict__ br,
                  const float* __restrict__ wout, const float* __restrict__ bout,
                  float* __restrict__ out, float* __restrict__ xbuf, int* __restrict__ flags)
{
  const int tid = threadIdx.x;
  const int p   = blockIdx.x & (BB - 1);   // batch item
  const int q   = blockIdx.x >> 7;         // half 0/1; (p, p+128) -> same XCD under %8
  const int hh  = tid & 1;                 // row half: rows [hh*160, hh*160+160)
  const int g   = (tid >> 1) & 3;          // 0=f,1=i,2=z,3=r
  const int c   = tid >> 3;                // channel within half [0,128)
  const int cg  = (q << 7) + c;            // global channel [0,256)

  __shared__ __align__(16) _Float16 uh[2][KR];   // [parity][ u(64) | h(256) ]
  __shared__ float yred[2][OO][33];              // padded partial y (32 chunks)

  // ---- register-resident half-column (fp16 pairs), 80 VGPRs ----
  int w2[NPH];
  const float* colp; int cstride;
  if (g < 3) { colp = kfiz + g * HH + cg; cstride = 3 * HH; }
  else       { colp = kr + cg;            cstride = HH;     }
  const int rbase = hh * (KR / 2);         // 0 or 160
#pragma unroll
  for (int k = 0; k < NPH; ++k) {
    f16x2 v;
    v.x = (_Float16)colp[(rbase + 2 * k    ) * cstride];
    v.y = (_Float16)colp[(rbase + 2 * k + 1) * cstride];
    w2[k] = __builtin_bit_cast(int, v);
  }
  const float bias = (g < 3) ? bfiz[g * HH + cg] : br[cg];

  // ---- W_out fragment: 32 chunks x 8 rows; 4 pairs = 4 VGPRs ----
  const int o  = tid & 31;
  const int jc = (tid >> 5) & 31;          // chunk [0,32)
  int wo2[4];
#pragma unroll
  for (int k = 0; k < 4; ++k) {
    f16x2 v;
    v.x = (_Float16)wout[(jc * 8 + 2 * k    ) * OO + o];
    v.y = (_Float16)wout[(jc * 8 + 2 * k + 1) * OO + o];
    wo2[k] = __builtin_bit_cast(int, v);
  }
  const float bo = bout[o];

  // ---- state init ----
  float cs = x0[p * 2 * HH + HH + cg];     // c0, replicated across 8 lanes/channel
  if (tid < HH) uh[0][DD + tid] = (_Float16)x0[p * 2 * HH + tid];           // h0
  if (tid < DD) uh[0][tid]      = (_Float16)u[((size_t)p * TT) * DD + tid]; // u_0

  float* xown = xbuf + (size_t)((p * 2 + q      ) * 2) * 128;
  float* xpar = xbuf + (size_t)((p * 2 + (q ^ 1)) * 2) * 128;
  int*   fown = flags + (p * 2 + q      ) * 16;
  int*   fpar = flags + (p * 2 + (q ^ 1)) * 16;

  const bool upf = (tid >= 1024 - DD);     // u-prefetch lanes (one wave)
  const int  uj  = tid - (1024 - DD);

  __syncthreads();

  for (int step = 0; step < TT; ++step) {
    const int cur = step & 1;
    const int nxt = cur ^ 1;

    // u_{step+1} load issued early; stored to LDS in P3
    float unext = 0.0f;
    if (upf && step + 1 < TT) unext = u[((size_t)p * TT + step + 1) * DD + uj];

    // ---- y partial for step-1 (h_{step-1} lives in uh[cur]) ----
    if (q == 0 && step > 0) {
      const int2* hp = (const int2*)&uh[cur][DD + jc * 8];
      int2 ha = hp[0], hb = hp[1];
      float ya = 0.0f;
      ya = fdot2(b2h(wo2[0]), b2h(ha.x), ya);
      ya = fdot2(b2h(wo2[1]), b2h(ha.y), ya);
      ya = fdot2(b2h(wo2[2]), b2h(hb.x), ya);
      ya = fdot2(b2h(wo2[3]), b2h(hb.y), ya);
      yred[cur][o][jc] = ya;
    }

    // ---- P1: 160-row half-dot, 4 independent fp32 chains ----
    const int4* up = (const int4*)&uh[cur][rbase];
    float a0 = (hh == 0) ? bias : 0.0f, a1 = 0.0f, a2 = 0.0f, a3 = 0.0f;
#pragma unroll
    for (int k = 0; k < 20; ++k) {
      int4 hv = up[k];                       // wave-uniform broadcast read
      a0 = fdot2(b2h(w2[4 * k + 0]), b2h(hv.x), a0);
      a1 = fdot2(b2h(w2[4 * k + 1]), b2h(hv.y), a1);
      a2 = fdot2(b2h(w2[4 * k + 2]), b2h(hv.z), a2);
      a3 = fdot2(b2h(w2[4 * k + 3]), b2h(hv.w), a3);
    }
    const float part = (a0 + a1) + (a2 + a3);
    const float pre  = part + __shfl_xor(part, 1);   // sum row halves

    // ---- P2: activate own gate, swap across the 4 gates (lane bits 1..2) ----
    const float act = (g == 3) ? tanhf_(pre) : sigm(pre);
    const float n1 = __shfl_xor(act, 2);   // gate g^1
    const float n2 = __shfl_xor(act, 4);   // gate g^2
    const float n3 = __shfl_xor(act, 6);   // gate g^3
    float f, i, z, r;
    { int m;
      m = g;     f = (m == 0) ? act : (m == 1) ? n1 : (m == 2) ? n2 : n3;
      m = g ^ 1; i = (m == 0) ? act : (m == 1) ? n1 : (m == 2) ? n2 : n3;
      m = g ^ 2; z = (m == 0) ? act : (m == 1) ? n1 : (m == 2) ? n2 : n3;
      m = g ^ 3; r = (m == 0) ? act : (m == 1) ? n1 : (m == 2) ? n2 : n3;
    }
    cs = f * cs + i * r;
    const float hn = z * tanhf_(cs);

    // ---- P3: publish own half ----
    if ((tid & 7) == 0) {                   // one lane per channel (g==0, hh==0)
      uh[nxt][DD + cg] = (_Float16)hn;
      __hip_atomic_store(&xown[nxt * 128 + c], hn, __ATOMIC_RELAXED, __HIP_MEMORY_SCOPE_AGENT);
    }
    if (upf && step + 1 < TT) uh[nxt][uj] = (_Float16)unext;
    __syncthreads();   // B: own X stores + uh[nxt] own half + yred[cur] complete

    if (tid == 0)
      __hip_atomic_store(fown, step + 1, __ATOMIC_RELEASE, __HIP_MEMORY_SCOPE_AGENT);

    // y reduce/store for step-1 (after flag, so partner is not stalled by this)
    if (q == 0 && step > 0 && tid < OO) {
      float s = bo;
#pragma unroll
      for (int k = 0; k < 32; ++k) s += yred[cur][tid][k];
      out[((size_t)p * TT + (step - 1)) * OO + tid] = s;
    }

    // ---- P4: fetch partner half (one lane per wave spins) ----
    if (tid >= 128 && tid < 256) {
      if ((tid & 63) == 0) {
        while (__hip_atomic_load(fpar, __ATOMIC_ACQUIRE, __HIP_MEMORY_SCOPE_AGENT) < step + 1) {}
      }
      const int j = tid & 127;
      const float hv = __hip_atomic_load(&xpar[nxt * 128 + j], __ATOMIC_RELAXED, __HIP_MEMORY_SCOPE_AGENT);
      uh[nxt][DD + ((q ^ 1) << 7) + j] = (_Float16)hv;
    }
    __syncthreads();   // C: uh[nxt] fully assembled for next step
  }

  // ---- epilogue: y_{T-1} from uh[0] (T even -> final h is in buffer 0) ----
  if (q == 0) {
    const int2* hp = (const int2*)&uh[0][DD + jc * 8];
    int2 ha = hp[0], hb = hp[1];
    float ya = 0.0f;
    ya = fdot2(b2h(wo2[0]), b2h(ha.x), ya);
    ya = fdot2(b2h(wo2[1]), b2h(ha.y), ya);
    ya = fdot2(b2h(wo2[2]), b2h(hb.x), ya);
    ya = fdot2(b2h(wo2[3]), b2h(hb.y), ya);
    yred[0][o][jc] = ya;
    __syncthreads();
    if (tid < OO) {
      float s = bo;
#pragma unroll
      for (int k = 0; k < 32; ++k) s += yred[0][tid][k];
      out[((size_t)p * TT + (TT - 1)) * OO + tid] = s;
    }
  }
}

extern "C" void kernel_launch(void* const* d_in, const int* in_sizes, int n_in,
                              void* d_out, int out_size, void* d_ws, size_t ws_size,
                              hipStream_t stream) {
  const float* u    = (const float*)d_in[0];
  const float* x0   = (const float*)d_in[1];
  const float* kfiz = (const float*)d_in[2];
  const float* bfiz = (const float*)d_in[3];
  const float* kr   = (const float*)d_in[4];
  const float* br   = (const float*)d_in[5];
  const float* wout = (const float*)d_in[6];
  const float* bout = (const float*)d_in[7];
  float* out  = (float*)d_out;
  // ws layout: X exchange buffer [128][2(half)][2(parity)][128] floats (256 KB),
  // then flags [128][2] ints at 64 B stride. 0xAA poison -> negative -> safe.
  float* xbuf = (float*)d_ws;
  int*   flg  = (int*)((char*)d_ws + (size_t)BB * 2 * 2 * 128 * sizeof(float));
  lstm_persist<<<dim3(2 * BB), dim3(1024), 0, stream>>>(
      u, x0, kfiz, bfiz, kr, br, wout, bout, out, xbuf, flg);
}

// Round 3
// 20491.835 us; speedup vs baseline: 1.0216x; 1.0216x over previous
//
#include <hip/hip_runtime.h>
#include <cstdint>
#include <cstddef>

// SingleLayerLSTM: B=128, T=2048, D=64, H=256, O=32.
// v3: kill the spill (empirical launch_bounds: 2nd arg acts as min-BLOCKS/CU;
//     v2's (1024,4) -> 64-VGPR cap -> 80-reg weight array spilled; (1024,1)
//     gives a 128-VGPR cap) and cut LDS broadcast volume 4x.
//  - 256 blocks x 1024 threads; block = (batch p = blk&127, half q = blk>>7).
//  - Thread = (channel c = tid>>3, row-octant rq = tid&7). Owns ALL 4 gates of
//    one column over 40 rows: w2[4][20] fp16-pairs = 80 VGPRs. LDS reads are
//    5x ds_read_b128/step (80 B) instead of 320 B -> LDS pipe no longer limits.
//  - Gate partials reduced across the 8 row-octants via shfl_xor(1,2,4)
//    butterfly; every lane then applies activations redundantly (cheap).
//  - [u_t | h_{t-1}] in LDS fp16, parity double-buffered; halves exchange h via
//    L2 buffer + release/acquire agent-scope flags (monotonic step counter;
//    0xAA poison is negative -> no init needed, graph-replay safe).
//  - y_{t-1} computed one step behind by q==0 blocks (32x32 partials + reduce).

#define HH 256
#define DD 64
#define TT 2048
#define BB 128
#define OO 32
#define KR 320   // D + H rows

typedef _Float16 f16x2 __attribute__((ext_vector_type(2)));

__device__ __forceinline__ f16x2 b2h(int v) { return __builtin_bit_cast(f16x2, v); }

#if __has_builtin(__builtin_amdgcn_fdot2)
__device__ __forceinline__ float fdot2(f16x2 a, f16x2 b, float c) {
  return __builtin_amdgcn_fdot2(a, b, c, false);
}
#else
__device__ __forceinline__ float fdot2(f16x2 a, f16x2 b, float c) {
  return fmaf((float)a.y, (float)b.y, fmaf((float)a.x, (float)b.x, c));
}
#endif

__device__ __forceinline__ float frcp(float x) { return __builtin_amdgcn_rcpf(x); }
__device__ __forceinline__ float sigm(float x)  { return frcp(1.0f + __expf(-x)); }
__device__ __forceinline__ float tanhf_(float x){ return 1.0f - 2.0f * frcp(1.0f + __expf(2.0f * x)); }

__global__ __launch_bounds__(1024, 1)
void lstm_persist(const float* __restrict__ u,    const float* __restrict__ x0,
                  const float* __restrict__ kfiz, const float* __restrict__ bfiz,
                  const float* __restrict__ kr,   const float* __restrict__ br,
                  const float* __restrict__ wout, const float* __restrict__ bout,
                  float* __restrict__ out, float* __restrict__ xbuf, int* __restrict__ flags)
{
  const int tid = threadIdx.x;
  const int p   = blockIdx.x & (BB - 1);   // batch item
  const int q   = blockIdx.x >> 7;         // half 0/1; (p, p+128) -> same XCD under %8
  const int rq  = tid & 7;                 // row octant: rows [rq*40, rq*40+40)
  const int c   = tid >> 3;                // channel within half [0,128)
  const int cg  = (q << 7) + c;            // global channel [0,256)

  __shared__ __align__(16) _Float16 uh[2][KR];   // [parity][ u(64) | h(256) ]
  __shared__ float yred[2][OO][33];              // padded partial y (32 chunks)

  // ---- register-resident weights: 4 gates x 40 rows = 80 fp16-pairs ----
  int w2[80];
#pragma unroll
  for (int g = 0; g < 4; ++g) {
    const float* colp = (g < 3) ? (kfiz + g * HH + cg) : (kr + cg);
    const int cstride = (g < 3) ? (3 * HH) : HH;
#pragma unroll
    for (int k = 0; k < 20; ++k) {
      f16x2 v;
      v.x = (_Float16)colp[(rq * 40 + 2 * k    ) * cstride];
      v.y = (_Float16)colp[(rq * 40 + 2 * k + 1) * cstride];
      w2[g * 20 + k] = __builtin_bit_cast(int, v);
    }
  }
  // bias folded into octant-0's accumulator init
  const float bf_ = (rq == 0) ? bfiz[0 * HH + cg] : 0.0f;
  const float bi_ = (rq == 0) ? bfiz[1 * HH + cg] : 0.0f;
  const float bz_ = (rq == 0) ? bfiz[2 * HH + cg] : 0.0f;
  const float br_ = (rq == 0) ? br[cg]            : 0.0f;

  // ---- W_out fragment: 32 chunks x 8 rows; 4 pairs ----
  const int o  = tid & 31;
  const int jc = (tid >> 5) & 31;          // chunk [0,32)
  int wo2[4];
#pragma unroll
  for (int k = 0; k < 4; ++k) {
    f16x2 v;
    v.x = (_Float16)wout[(jc * 8 + 2 * k    ) * OO + o];
    v.y = (_Float16)wout[(jc * 8 + 2 * k + 1) * OO + o];
    wo2[k] = __builtin_bit_cast(int, v);
  }
  const float bo = bout[o];

  // ---- state init ----
  float cs = x0[p * 2 * HH + HH + cg];     // c0, replicated across 8 lanes/channel
  if (tid < HH) uh[0][DD + tid] = (_Float16)x0[p * 2 * HH + tid];           // h0
  if (tid < DD) uh[0][tid]      = (_Float16)u[((size_t)p * TT) * DD + tid]; // u_0

  float* xown = xbuf + (size_t)((p * 2 + q      ) * 2) * 128;
  float* xpar = xbuf + (size_t)((p * 2 + (q ^ 1)) * 2) * 128;
  int*   fown = flags + (p * 2 + q      ) * 16;
  int*   fpar = flags + (p * 2 + (q ^ 1)) * 16;

  const bool upf = (tid >= 1024 - DD);     // u-prefetch lanes (one wave)
  const int  uj  = tid - (1024 - DD);

  __syncthreads();

  for (int step = 0; step < TT; ++step) {
    const int cur = step & 1;
    const int nxt = cur ^ 1;

    // u_{step+1} issued early; stored to LDS in P3
    float unext = 0.0f;
    if (upf && step + 1 < TT) unext = u[((size_t)p * TT + step + 1) * DD + uj];

    // ---- y partial for step-1 (h_{step-1} lives in uh[cur]) ----
    if (q == 0 && step > 0) {
      const int2* hp = (const int2*)&uh[cur][DD + jc * 8];
      int2 ha = hp[0], hb = hp[1];
      float ya = 0.0f;
      ya = fdot2(b2h(wo2[0]), b2h(ha.x), ya);
      ya = fdot2(b2h(wo2[1]), b2h(ha.y), ya);
      ya = fdot2(b2h(wo2[2]), b2h(hb.x), ya);
      ya = fdot2(b2h(wo2[3]), b2h(hb.y), ya);
      yred[cur][o][jc] = ya;
    }

    // ---- P1: 40-row slab, all 4 gates (4 independent fp32 chains) ----
    const int4* up = (const int4*)&uh[cur][rq * 40];   // 80 B, 16-aligned
    float af = bf_, ai = bi_, az = bz_, ar = br_;
#pragma unroll
    for (int j = 0; j < 5; ++j) {
      int4 hv = up[j];                       // 8-way broadcast, conflict-free
      f16x2 h0 = b2h(hv.x), h1 = b2h(hv.y), h2 = b2h(hv.z), h3 = b2h(hv.w);
      af = fdot2(b2h(w2[ 0 + 4 * j + 0]), h0, af);
      af = fdot2(b2h(w2[ 0 + 4 * j + 1]), h1, af);
      af = fdot2(b2h(w2[ 0 + 4 * j + 2]), h2, af);
      af = fdot2(b2h(w2[ 0 + 4 * j + 3]), h3, af);
      ai = fdot2(b2h(w2[20 + 4 * j + 0]), h0, ai);
      ai = fdot2(b2h(w2[20 + 4 * j + 1]), h1, ai);
      ai = fdot2(b2h(w2[20 + 4 * j + 2]), h2, ai);
      ai = fdot2(b2h(w2[20 + 4 * j + 3]), h3, ai);
      az = fdot2(b2h(w2[40 + 4 * j + 0]), h0, az);
      az = fdot2(b2h(w2[40 + 4 * j + 1]), h1, az);
      az = fdot2(b2h(w2[40 + 4 * j + 2]), h2, az);
      az = fdot2(b2h(w2[40 + 4 * j + 3]), h3, az);
      ar = fdot2(b2h(w2[60 + 4 * j + 0]), h0, ar);
      ar = fdot2(b2h(w2[60 + 4 * j + 1]), h1, ar);
      ar = fdot2(b2h(w2[60 + 4 * j + 2]), h2, ar);
      ar = fdot2(b2h(w2[60 + 4 * j + 3]), h3, ar);
    }

    // ---- P2: butterfly-reduce octants (rq = lane bits 0..2) ----
    af += __shfl_xor(af, 1); ai += __shfl_xor(ai, 1);
    az += __shfl_xor(az, 1); ar += __shfl_xor(ar, 1);
    af += __shfl_xor(af, 2); ai += __shfl_xor(ai, 2);
    az += __shfl_xor(az, 2); ar += __shfl_xor(ar, 2);
    af += __shfl_xor(af, 4); ai += __shfl_xor(ai, 4);
    az += __shfl_xor(az, 4); ar += __shfl_xor(ar, 4);

    const float f = sigm(af), i = sigm(ai), z = sigm(az), r = tanhf_(ar);
    cs = f * cs + i * r;
    const float hn = z * tanhf_(cs);

    // ---- P3: publish own half ----
    if (rq == 0) {
      uh[nxt][DD + cg] = (_Float16)hn;
      __hip_atomic_store(&xown[nxt * 128 + c], hn, __ATOMIC_RELAXED, __HIP_MEMORY_SCOPE_AGENT);
    }
    if (upf && step + 1 < TT) uh[nxt][uj] = (_Float16)unext;
    __syncthreads();   // B: own X stores + uh[nxt] own half + yred[cur] complete

    if (tid == 0)
      __hip_atomic_store(fown, step + 1, __ATOMIC_RELEASE, __HIP_MEMORY_SCOPE_AGENT);

    // y reduce/store for step-1 (after flag, so partner is not stalled)
    if (q == 0 && step > 0 && tid < OO) {
      float s = bo;
#pragma unroll
      for (int k = 0; k < 32; ++k) s += yred[cur][tid][k];
      out[((size_t)p * TT + (step - 1)) * OO + tid] = s;
    }

    // ---- P4: fetch partner half (one lane per wave spins) ----
    if (tid >= 128 && tid < 256) {
      if ((tid & 63) == 0) {
        while (__hip_atomic_load(fpar, __ATOMIC_ACQUIRE, __HIP_MEMORY_SCOPE_AGENT) < step + 1) {}
      }
      const int j = tid & 127;
      const float hv = __hip_atomic_load(&xpar[nxt * 128 + j], __ATOMIC_RELAXED, __HIP_MEMORY_SCOPE_AGENT);
      uh[nxt][DD + ((q ^ 1) << 7) + j] = (_Float16)hv;
    }
    __syncthreads();   // C: uh[nxt] fully assembled for next step
  }

  // ---- epilogue: y_{T-1} from uh[0] (T even -> final h is in buffer 0) ----
  if (q == 0) {
    const int2* hp = (const int2*)&uh[0][DD + jc * 8];
    int2 ha = hp[0], hb = hp[1];
    float ya = 0.0f;
    ya = fdot2(b2h(wo2[0]), b2h(ha.x), ya);
    ya = fdot2(b2h(wo2[1]), b2h(ha.y), ya);
    ya = fdot2(b2h(wo2[2]), b2h(hb.x), ya);
    ya = fdot2(b2h(wo2[3]), b2h(hb.y), ya);
    yred[0][o][jc] = ya;
    __syncthreads();
    if (tid < OO) {
      float s = bo;
#pragma unroll
      for (int k = 0; k < 32; ++k) s += yred[0][tid][k];
      out[((size_t)p * TT + (TT - 1)) * OO + tid] = s;
    }
  }
}

extern "C" void kernel_launch(void* const* d_in, const int* in_sizes, int n_in,
                              void* d_out, int out_size, void* d_ws, size_t ws_size,
                              hipStream_t stream) {
  const float* u    = (const float*)d_in[0];
  const float* x0   = (const float*)d_in[1];
  const float* kfiz = (const float*)d_in[2];
  const float* bfiz = (const float*)d_in[3];
  const float* kr   = (const float*)d_in[4];
  const float* br   = (const float*)d_in[5];
  const float* wout = (const float*)d_in[6];
  const float* bout = (const float*)d_in[7];
  float* out  = (float*)d_out;
  // ws layout: X exchange buffer [128][2(half)][2(parity)][128] floats (256 KB),
  // then flags [128][2] ints at 64 B stride. 0xAA poison -> negative -> safe.
  float* xbuf = (float*)d_ws;
  int*   flg  = (int*)((char*)d_ws + (size_t)BB * 2 * 2 * 128 * sizeof(float));
  lstm_persist<<<dim3(2 * BB), dim3(1024), 0, stream>>>(
      u, x0, kfiz, bfiz, kr, br, wout, bout, out, xbuf, flg);
}

// Round 4
// 20113.879 us; speedup vs baseline: 1.0408x; 1.0188x over previous
//
#include <hip/hip_runtime.h>
#include <cstdint>
#include <cstddef>

// SingleLayerLSTM: B=128, T=2048, D=64, H=256, O=32.
// v4 = v3 + amdgpu_waves_per_eu(4,4) to pin the register allocator.
// Evidence R1-R3: launch_bounds' 2nd arg is only a FLOOR on waves/EU; the
// backend targets 8 waves/EU (64 VGPRs) and spills the 80-reg weight array to
// scratch (VGPR_Count=64, VALUBusy ~10%, 10us/step of L2/L3 scratch reloads).
// waves_per_eu(4,4) pins occupancy to 4 waves/EU -> 128-VGPR budget -> weights
// stay register-resident. 1 block (16 waves) per CU is what we had anyway.
//  - 256 blocks x 1024 threads; block = (batch p = blk&127, half q = blk>>7).
//  - Thread = (channel c = tid>>3, row-octant rq = tid&7). Owns all 4 gates of
//    one column over 40 rows: w2[4][20] fp16-pairs = 80 VGPRs.
//  - [u_t | h_{t-1}] in LDS fp16 parity double-buffered; matvec reads are
//    5x ds_read_b128/thread/step, 8-way broadcast, conflict-free (measured 0).
//  - Gate partials reduced across 8 row-octants via shfl_xor(1,2,4) butterfly.
//  - Halves exchange h via L2 buffer + release/acquire agent-scope flags
//    (monotonic step counter; 0xAA poison is negative -> no init needed).
//  - y_{t-1} computed one step behind by q==0 blocks (32x32 partials + reduce).

#define HH 256
#define DD 64
#define TT 2048
#define BB 128
#define OO 32
#define KR 320   // D + H rows

typedef _Float16 f16x2 __attribute__((ext_vector_type(2)));

__device__ __forceinline__ f16x2 b2h(int v) { return __builtin_bit_cast(f16x2, v); }

#if __has_builtin(__builtin_amdgcn_fdot2)
__device__ __forceinline__ float fdot2(f16x2 a, f16x2 b, float c) {
  return __builtin_amdgcn_fdot2(a, b, c, false);
}
#else
__device__ __forceinline__ float fdot2(f16x2 a, f16x2 b, float c) {
  return fmaf((float)a.y, (float)b.y, fmaf((float)a.x, (float)b.x, c));
}
#endif

__device__ __forceinline__ float frcp(float x) { return __builtin_amdgcn_rcpf(x); }
__device__ __forceinline__ float sigm(float x)  { return frcp(1.0f + __expf(-x)); }
__device__ __forceinline__ float tanhf_(float x){ return 1.0f - 2.0f * frcp(1.0f + __expf(2.0f * x)); }

__global__
__attribute__((amdgpu_flat_work_group_size(1024, 1024)))
__attribute__((amdgpu_waves_per_eu(4, 4)))
void lstm_persist(const float* __restrict__ u,    const float* __restrict__ x0,
                  const float* __restrict__ kfiz, const float* __restrict__ bfiz,
                  const float* __restrict__ kr,   const float* __restrict__ br,
                  const float* __restrict__ wout, const float* __restrict__ bout,
                  float* __restrict__ out, float* __restrict__ xbuf, int* __restrict__ flags)
{
  const int tid = threadIdx.x;
  const int p   = blockIdx.x & (BB - 1);   // batch item
  const int q   = blockIdx.x >> 7;         // half 0/1; (p, p+128) -> same XCD under %8
  const int rq  = tid & 7;                 // row octant: rows [rq*40, rq*40+40)
  const int c   = tid >> 3;                // channel within half [0,128)
  const int cg  = (q << 7) + c;            // global channel [0,256)

  __shared__ __align__(16) _Float16 uh[2][KR];   // [parity][ u(64) | h(256) ]
  __shared__ float yred[2][OO][33];              // padded partial y (32 chunks)

  // ---- register-resident weights: 4 gates x 40 rows = 80 fp16-pairs ----
  int w2[80];
#pragma unroll
  for (int g = 0; g < 4; ++g) {
    const float* colp = (g < 3) ? (kfiz + g * HH + cg) : (kr + cg);
    const int cstride = (g < 3) ? (3 * HH) : HH;
#pragma unroll
    for (int k = 0; k < 20; ++k) {
      f16x2 v;
      v.x = (_Float16)colp[(rq * 40 + 2 * k    ) * cstride];
      v.y = (_Float16)colp[(rq * 40 + 2 * k + 1) * cstride];
      w2[g * 20 + k] = __builtin_bit_cast(int, v);
    }
  }
  // bias folded into octant-0's accumulator init
  const float bf_ = (rq == 0) ? bfiz[0 * HH + cg] : 0.0f;
  const float bi_ = (rq == 0) ? bfiz[1 * HH + cg] : 0.0f;
  const float bz_ = (rq == 0) ? bfiz[2 * HH + cg] : 0.0f;
  const float br_ = (rq == 0) ? br[cg]            : 0.0f;

  // ---- W_out fragment: 32 chunks x 8 rows; 4 pairs ----
  const int o  = tid & 31;
  const int jc = (tid >> 5) & 31;          // chunk [0,32)
  int wo2[4];
#pragma unroll
  for (int k = 0; k < 4; ++k) {
    f16x2 v;
    v.x = (_Float16)wout[(jc * 8 + 2 * k    ) * OO + o];
    v.y = (_Float16)wout[(jc * 8 + 2 * k + 1) * OO + o];
    wo2[k] = __builtin_bit_cast(int, v);
  }
  const float bo = bout[o];

  // ---- state init ----
  float cs = x0[p * 2 * HH + HH + cg];     // c0, replicated across 8 lanes/channel
  if (tid < HH) uh[0][DD + tid] = (_Float16)x0[p * 2 * HH + tid];           // h0
  if (tid < DD) uh[0][tid]      = (_Float16)u[((size_t)p * TT) * DD + tid]; // u_0

  float* xown = xbuf + (size_t)((p * 2 + q      ) * 2) * 128;
  float* xpar = xbuf + (size_t)((p * 2 + (q ^ 1)) * 2) * 128;
  int*   fown = flags + (p * 2 + q      ) * 16;
  int*   fpar = flags + (p * 2 + (q ^ 1)) * 16;

  const bool upf = (tid >= 1024 - DD);     // u-prefetch lanes (one wave)
  const int  uj  = tid - (1024 - DD);

  __syncthreads();

  for (int step = 0; step < TT; ++step) {
    const int cur = step & 1;
    const int nxt = cur ^ 1;

    // u_{step+1} issued early; stored to LDS in P3
    float unext = 0.0f;
    if (upf && step + 1 < TT) unext = u[((size_t)p * TT + step + 1) * DD + uj];

    // ---- y partial for step-1 (h_{step-1} lives in uh[cur]) ----
    if (q == 0 && step > 0) {
      const int2* hp = (const int2*)&uh[cur][DD + jc * 8];
      int2 ha = hp[0], hb = hp[1];
      float ya = 0.0f;
      ya = fdot2(b2h(wo2[0]), b2h(ha.x), ya);
      ya = fdot2(b2h(wo2[1]), b2h(ha.y), ya);
      ya = fdot2(b2h(wo2[2]), b2h(hb.x), ya);
      ya = fdot2(b2h(wo2[3]), b2h(hb.y), ya);
      yred[cur][o][jc] = ya;
    }

    // ---- P1: 40-row slab, all 4 gates (4 independent fp32 chains) ----
    const int4* up = (const int4*)&uh[cur][rq * 40];   // 80 B stride, 16-aligned
    float af = bf_, ai = bi_, az = bz_, ar = br_;
#pragma unroll
    for (int j = 0; j < 5; ++j) {
      int4 hv = up[j];                       // 8-way broadcast, conflict-free
      f16x2 h0 = b2h(hv.x), h1 = b2h(hv.y), h2 = b2h(hv.z), h3 = b2h(hv.w);
      af = fdot2(b2h(w2[ 0 + 4 * j + 0]), h0, af);
      af = fdot2(b2h(w2[ 0 + 4 * j + 1]), h1, af);
      af = fdot2(b2h(w2[ 0 + 4 * j + 2]), h2, af);
      af = fdot2(b2h(w2[ 0 + 4 * j + 3]), h3, af);
      ai = fdot2(b2h(w2[20 + 4 * j + 0]), h0, ai);
      ai = fdot2(b2h(w2[20 + 4 * j + 1]), h1, ai);
      ai = fdot2(b2h(w2[20 + 4 * j + 2]), h2, ai);
      ai = fdot2(b2h(w2[20 + 4 * j + 3]), h3, ai);
      az = fdot2(b2h(w2[40 + 4 * j + 0]), h0, az);
      az = fdot2(b2h(w2[40 + 4 * j + 1]), h1, az);
      az = fdot2(b2h(w2[40 + 4 * j + 2]), h2, az);
      az = fdot2(b2h(w2[40 + 4 * j + 3]), h3, az);
      ar = fdot2(b2h(w2[60 + 4 * j + 0]), h0, ar);
      ar = fdot2(b2h(w2[60 + 4 * j + 1]), h1, ar);
      ar = fdot2(b2h(w2[60 + 4 * j + 2]), h2, ar);
      ar = fdot2(b2h(w2[60 + 4 * j + 3]), h3, ar);
    }

    // ---- P2: butterfly-reduce octants (rq = lane bits 0..2) ----
    af += __shfl_xor(af, 1); ai += __shfl_xor(ai, 1);
    az += __shfl_xor(az, 1); ar += __shfl_xor(ar, 1);
    af += __shfl_xor(af, 2); ai += __shfl_xor(ai, 2);
    az += __shfl_xor(az, 2); ar += __shfl_xor(ar, 2);
    af += __shfl_xor(af, 4); ai += __shfl_xor(ai, 4);
    az += __shfl_xor(az, 4); ar += __shfl_xor(ar, 4);

    const float f = sigm(af), i = sigm(ai), z = sigm(az), r = tanhf_(ar);
    cs = f * cs + i * r;
    const float hn = z * tanhf_(cs);

    // ---- P3: publish own half ----
    if (rq == 0) {
      uh[nxt][DD + cg] = (_Float16)hn;
      __hip_atomic_store(&xown[nxt * 128 + c], hn, __ATOMIC_RELAXED, __HIP_MEMORY_SCOPE_AGENT);
    }
    if (upf && step + 1 < TT) uh[nxt][uj] = (_Float16)unext;
    __syncthreads();   // B: own X stores + uh[nxt] own half + yred[cur] complete

    if (tid == 0)
      __hip_atomic_store(fown, step + 1, __ATOMIC_RELEASE, __HIP_MEMORY_SCOPE_AGENT);

    // y reduce/store for step-1 (after flag, so partner is not stalled)
    if (q == 0 && step > 0 && tid < OO) {
      float s = bo;
#pragma unroll
      for (int k = 0; k < 32; ++k) s += yred[cur][tid][k];
      out[((size_t)p * TT + (step - 1)) * OO + tid] = s;
    }

    // ---- P4: fetch partner half (one lane per wave spins) ----
    if (tid >= 128 && tid < 256) {
      if ((tid & 63) == 0) {
        while (__hip_atomic_load(fpar, __ATOMIC_ACQUIRE, __HIP_MEMORY_SCOPE_AGENT) < step + 1) {}
      }
      const int j = tid & 127;
      const float hv = __hip_atomic_load(&xpar[nxt * 128 + j], __ATOMIC_RELAXED, __HIP_MEMORY_SCOPE_AGENT);
      uh[nxt][DD + ((q ^ 1) << 7) + j] = (_Float16)hv;
    }
    __syncthreads();   // C: uh[nxt] fully assembled for next step
  }

  // ---- epilogue: y_{T-1} from uh[0] (T even -> final h is in buffer 0) ----
  if (q == 0) {
    const int2* hp = (const int2*)&uh[0][DD + jc * 8];
    int2 ha = hp[0], hb = hp[1];
    float ya = 0.0f;
    ya = fdot2(b2h(wo2[0]), b2h(ha.x), ya);
    ya = fdot2(b2h(wo2[1]), b2h(ha.y), ya);
    ya = fdot2(b2h(wo2[2]), b2h(hb.x), ya);
    ya = fdot2(b2h(wo2[3]), b2h(hb.y), ya);
    yred[0][o][jc] = ya;
    __syncthreads();
    if (tid < OO) {
      float s = bo;
#pragma unroll
      for (int k = 0; k < 32; ++k) s += yred[0][tid][k];
      out[((size_t)p * TT + (TT - 1)) * OO + tid] = s;
    }
  }
}

extern "C" void kernel_launch(void* const* d_in, const int* in_sizes, int n_in,
                              void* d_out, int out_size, void* d_ws, size_t ws_size,
                              hipStream_t stream) {
  const float* u    = (const float*)d_in[0];
  const float* x0   = (const float*)d_in[1];
  const float* kfiz = (const float*)d_in[2];
  const float* bfiz = (const float*)d_in[3];
  const float* kr   = (const float*)d_in[4];
  const float* br   = (const float*)d_in[5];
  const float* wout = (const float*)d_in[6];
  const float* bout = (const float*)d_in[7];
  float* out  = (float*)d_out;
  // ws layout: X exchange buffer [128][2(half)][2(parity)][128] floats (256 KB),
  // then flags [128][2] ints at 64 B stride. 0xAA poison -> negative -> safe.
  float* xbuf = (float*)d_ws;
  int*   flg  = (int*)((char*)d_ws + (size_t)BB * 2 * 2 * 128 * sizeof(float));
  lstm_persist<<<dim3(2 * BB), dim3(1024), 0, stream>>>(
      u, x0, kfiz, bfiz, kr, br, wout, bout, out, xbuf, flg);
}

// Round 5
// 7306.866 us; speedup vs baseline: 2.8650x; 2.7527x over previous
//
#include <hip/hip_runtime.h>
#include <cstdint>
#include <cstddef>

// SingleLayerLSTM: B=128, T=2048, D=64, H=256, O=32.
// v5: quad-split, 64-VGPR-budget design + fence-free tagged exchange.
// Evidence R1-R4: backend pins VGPR_Count=64 regardless of launch_bounds /
// waves_per_eu -> design per-thread state to FIT 64 (40 weight regs).
// Old release/acquire agent handshake emitted buffer_inv/buffer_wbl2 every
// poll -> L2 wrecked every step -> 10us/step of L3 refills. Now: data+tag
// packed in one u32, RELAXED agent atomics only (no cache maintenance).
//  - 512 blocks x 1024 thr; item p = blk>>2, quarter q4 = blk&3 (2 blocks/CU).
//  - Thread (c = tid>>4 in [0,64), rq = tid&15): all 4 gates of channel
//    q4*64+c over rows [rq*20, rq*20+20) -> w2[4][10] fp16-pairs = 40 VGPRs.
//  - [u_t | h_t] in LDS fp16, parity double-buffered; P1 reads 5x ds_read_b64,
//    16-slice layout covers all 32 banks, 4-way broadcast -> conflict-free.
//  - Reduction across 16 row-slices: 4x v_add_f32 row_ror DPP (VALU pipe, no
//    LDS) -> every lane holds all 4 gate sums -> redundant activations.
//  - h exchange: xw[item][parity][256] u32 = (ver<<16)|fp16; producers store
//    relaxed, consumers poll tag==ver. Poison tag 0xAAAA never matches ->
//    graph-replay safe with no init. Skew bounded by step dependency chain.
//  - y_{t-1}: each block computes its 8 output cols (lanes 256..383 partials,
//    lanes 384..391 reduce+store) one step behind.

#define HH 256
#define DD 64
#define TT 2048
#define BB 128
#define OO 32
#define KR 320

typedef _Float16 f16x2 __attribute__((ext_vector_type(2)));

__device__ __forceinline__ f16x2 b2h(int v) { return __builtin_bit_cast(f16x2, v); }
__device__ __forceinline__ int h2b(f16x2 v) { return __builtin_bit_cast(int, v); }

#if __has_builtin(__builtin_amdgcn_fdot2)
__device__ __forceinline__ float fdot2(f16x2 a, f16x2 b, float c) {
  return __builtin_amdgcn_fdot2(a, b, c, false);
}
#else
__device__ __forceinline__ float fdot2(f16x2 a, f16x2 b, float c) {
  return fmaf((float)a.y, (float)b.y, fmaf((float)a.x, (float)b.x, c));
}
#endif

__device__ __forceinline__ float frcp(float x) { return __builtin_amdgcn_rcpf(x); }
__device__ __forceinline__ float sigm(float x)  { return frcp(1.0f + __expf(-x)); }
__device__ __forceinline__ float tanhf_(float x){ return 1.0f - 2.0f * frcp(1.0f + __expf(2.0f * x)); }

// all-reduce over the 16-lane DPP row via row_ror rotations (VALU pipe)
#if __has_builtin(__builtin_amdgcn_update_dpp)
#define ROR_ADD16(x) do { \
  x += __builtin_bit_cast(float, __builtin_amdgcn_update_dpp(0, __builtin_bit_cast(int, x), 0x121, 0xf, 0xf, true)); \
  x += __builtin_bit_cast(float, __builtin_amdgcn_update_dpp(0, __builtin_bit_cast(int, x), 0x122, 0xf, 0xf, true)); \
  x += __builtin_bit_cast(float, __builtin_amdgcn_update_dpp(0, __builtin_bit_cast(int, x), 0x124, 0xf, 0xf, true)); \
  x += __builtin_bit_cast(float, __builtin_amdgcn_update_dpp(0, __builtin_bit_cast(int, x), 0x128, 0xf, 0xf, true)); \
} while (0)
#else
#define ROR_ADD16(x) do { \
  x += __shfl_xor(x, 1); x += __shfl_xor(x, 2); \
  x += __shfl_xor(x, 4); x += __shfl_xor(x, 8); \
} while (0)
#endif

__global__ __launch_bounds__(1024)
void lstm_quad(const float* __restrict__ u,    const float* __restrict__ x0,
               const float* __restrict__ kfiz, const float* __restrict__ bfiz,
               const float* __restrict__ kr,   const float* __restrict__ br,
               const float* __restrict__ wout, const float* __restrict__ bout,
               float* __restrict__ out, unsigned int* __restrict__ xw)
{
  const int tid = threadIdx.x;
  const int p   = blockIdx.x >> 2;         // batch item; items never span the
  const int q4  = blockIdx.x & 3;          // 256-block residency boundary
  const int c   = tid >> 4;                // channel within quarter [0,64)
  const int rq  = tid & 15;                // row slice: rows [rq*20, rq*20+20)
  const int cg  = q4 * 64 + c;             // global channel [0,256)

  __shared__ __align__(16) _Float16 uh[2][KR];     // [parity][ u(64) | h(256) ]
  __shared__ float yred[2][8][17];                 // y partials, padded
  __shared__ __align__(16) int wopk[16 * 8 * 8];   // W_out pairs [jc][o][k]

  // ---- register-resident weights: 4 gates x 10 pairs = 40 VGPRs ----
  int w2[40];
#pragma unroll
  for (int g = 0; g < 4; ++g) {
    const float* colp = (g < 3) ? (kfiz + g * HH + cg) : (kr + cg);
    const int cst = (g < 3) ? 3 * HH : HH;
#pragma unroll
    for (int k = 0; k < 10; ++k) {
      f16x2 v;
      v.x = (_Float16)colp[(rq * 20 + 2 * k    ) * cst];
      v.y = (_Float16)colp[(rq * 20 + 2 * k + 1) * cst];
      w2[g * 10 + k] = h2b(v);
    }
  }
  const float bf_ = bfiz[0 * HH + cg];
  const float bi_ = bfiz[1 * HH + cg];
  const float bz_ = bfiz[2 * HH + cg];
  const float br_ = br[cg];

  // ---- W_out fp16-pair staging into LDS (this block's 8 output cols) ----
  {
    const int jc = tid >> 6, o = (tid >> 3) & 7, k = tid & 7;   // covers 1024
    f16x2 v;
    v.x = (_Float16)wout[(jc * 16 + 2 * k    ) * OO + q4 * 8 + o];
    v.y = (_Float16)wout[(jc * 16 + 2 * k + 1) * OO + q4 * 8 + o];
    wopk[tid] = h2b(v);
  }
  const float bo = (tid >= 384 && tid < 392) ? bout[q4 * 8 + (tid - 384)] : 0.0f;

  // ---- state init ----
  float cs = x0[p * 2 * HH + HH + cg];     // c0, replicated over 16 rq lanes
  if (tid < HH) uh[0][DD + tid] = (_Float16)x0[p * 2 * HH + tid];
  if (tid >= 1024 - DD) {
    const int uj = tid - (1024 - DD);
    uh[0][uj] = (_Float16)u[((size_t)p * TT) * DD + uj];
  }

  unsigned int* xwp = xw + (size_t)p * 2 * 256;    // [parity][256]
  // consumer channel map: skip own quarter
  const int chp = (tid < q4 * 64) ? tid : tid + 64;  // valid for tid<192

  __syncthreads();

  for (int s = 0; s < TT; ++s) {
    const int cur = s & 1;
    const int nxt = cur ^ 1;

    // u_{s+1} issued early (lanes 960..1023)
    float unext = 0.0f;
    if (tid >= 1024 - DD && s + 1 < TT)
      unext = u[((size_t)p * TT + s + 1) * DD + (tid - (1024 - DD))];

    // ---- y stage1: partials of y_{s-1} from h_s in uh[cur] (lanes 256..383) ----
    if (s > 0 && tid >= 256 && tid < 384) {
      const int idx = tid - 256, o = idx & 7, jc = idx >> 3;   // jc in [0,16)
      const int4* hp = (const int4*)&uh[cur][DD + jc * 16];
      const int4* wp = (const int4*)&wopk[(jc * 8 + o) * 8];
      int4 ha = hp[0], hb = hp[1];
      int4 wa = wp[0], wb = wp[1];
      float ya = 0.0f;
      ya = fdot2(b2h(wa.x), b2h(ha.x), ya);
      ya = fdot2(b2h(wa.y), b2h(ha.y), ya);
      ya = fdot2(b2h(wa.z), b2h(ha.z), ya);
      ya = fdot2(b2h(wa.w), b2h(ha.w), ya);
      ya = fdot2(b2h(wb.x), b2h(hb.x), ya);
      ya = fdot2(b2h(wb.y), b2h(hb.y), ya);
      ya = fdot2(b2h(wb.z), b2h(hb.z), ya);
      ya = fdot2(b2h(wb.w), b2h(hb.w), ya);
      yred[cur][o][jc] = ya;
    }

    // ---- P1: 20-row slab, 4 gates (4 fp32 chains, 5x ds_read_b64) ----
    const int2* up = (const int2*)&uh[cur][rq * 20];
    float af = 0.0f, ai = 0.0f, az = 0.0f, ar = 0.0f;
#pragma unroll
    for (int j = 0; j < 5; ++j) {
      int2 hv = up[j];
      f16x2 h0 = b2h(hv.x), h1 = b2h(hv.y);
      af = fdot2(b2h(w2[ 0 + 2 * j]), h0, af);
      af = fdot2(b2h(w2[ 1 + 2 * j]), h1, af);
      ai = fdot2(b2h(w2[10 + 2 * j]), h0, ai);
      ai = fdot2(b2h(w2[11 + 2 * j]), h1, ai);
      az = fdot2(b2h(w2[20 + 2 * j]), h0, az);
      az = fdot2(b2h(w2[21 + 2 * j]), h1, az);
      ar = fdot2(b2h(w2[30 + 2 * j]), h0, ar);
      ar = fdot2(b2h(w2[31 + 2 * j]), h1, ar);
    }
    // wait: pairs per gate are interleaved 2 per j; fix indexing below.
    // (w2[g*10 + 2j] covers rows 4j..4j+1, w2[g*10+2j+1] rows 4j+2..4j+3)

    // ---- P2: DPP all-reduce over 16 row slices, redundant activations ----
    ROR_ADD16(af); ROR_ADD16(ai); ROR_ADD16(az); ROR_ADD16(ar);
    const float f = sigm(af + bf_), i = sigm(ai + bi_);
    const float z = sigm(az + bz_), r = tanhf_(ar + br_);
    cs = f * cs + i * r;
    const float hn = z * tanhf_(cs);

    // ---- P3: publish own channel (version s+1, parity nxt) ----
    if (rq == 0) {
      uh[nxt][DD + cg] = (_Float16)hn;
      const unsigned int hb16 =
          (unsigned int)__builtin_bit_cast(unsigned short, (_Float16)hn);
      __hip_atomic_store(&xwp[nxt * 256 + cg],
                         ((unsigned int)(s + 1) << 16) | hb16,
                         __ATOMIC_RELAXED, __HIP_MEMORY_SCOPE_AGENT);
    }
    if (tid >= 1024 - DD && s + 1 < TT)
      uh[nxt][tid - (1024 - DD)] = (_Float16)unext;
    __syncthreads();   // B: yred + uh[nxt] own part complete

    // ---- y stage2: reduce + store y_{s-1} (lanes 384..391) ----
    if (s > 0 && tid >= 384 && tid < 392) {
      const int o = tid - 384;
      float ssum = bo;
#pragma unroll
      for (int k = 0; k < 16; ++k) ssum += yred[cur][o][k];
      out[((size_t)p * TT + (s - 1)) * OO + q4 * 8 + o] = ssum;
    }

    // ---- P4: poll partner channels (lanes 0..191), tag == s+1 ----
    if (tid < 192) {
      const unsigned int want = (unsigned int)(s + 1) << 16;
      unsigned int v;
      do {
        v = __hip_atomic_load(&xwp[nxt * 256 + chp],
                              __ATOMIC_RELAXED, __HIP_MEMORY_SCOPE_AGENT);
      } while ((v & 0xffff0000u) != want);
      uh[nxt][DD + chp] =
          __builtin_bit_cast(_Float16, (unsigned short)(v & 0xffffu));
    }
    __syncthreads();   // C: uh[nxt] fully assembled
  }

  // ---- epilogue: y_{T-1} from h_T in uh[0] ----
  if (tid >= 256 && tid < 384) {
    const int idx = tid - 256, o = idx & 7, jc = idx >> 3;
    const int4* hp = (const int4*)&uh[0][DD + jc * 16];
    const int4* wp = (const int4*)&wopk[(jc * 8 + o) * 8];
    int4 ha = hp[0], hb = hp[1];
    int4 wa = wp[0], wb = wp[1];
    float ya = 0.0f;
    ya = fdot2(b2h(wa.x), b2h(ha.x), ya);
    ya = fdot2(b2h(wa.y), b2h(ha.y), ya);
    ya = fdot2(b2h(wa.z), b2h(ha.z), ya);
    ya = fdot2(b2h(wa.w), b2h(ha.w), ya);
    ya = fdot2(b2h(wb.x), b2h(hb.x), ya);
    ya = fdot2(b2h(wb.y), b2h(hb.y), ya);
    ya = fdot2(b2h(wb.z), b2h(hb.z), ya);
    ya = fdot2(b2h(wb.w), b2h(hb.w), ya);
    yred[0][o][jc] = ya;
  }
  __syncthreads();
  if (tid >= 384 && tid < 392) {
    const int o = tid - 384;
    float ssum = bo;
#pragma unroll
    for (int k = 0; k < 16; ++k) ssum += yred[0][o][k];
    out[((size_t)p * TT + (TT - 1)) * OO + q4 * 8 + o] = ssum;
  }
}

extern "C" void kernel_launch(void* const* d_in, const int* in_sizes, int n_in,
                              void* d_out, int out_size, void* d_ws, size_t ws_size,
                              hipStream_t stream) {
  const float* u    = (const float*)d_in[0];
  const float* x0   = (const float*)d_in[1];
  const float* kfiz = (const float*)d_in[2];
  const float* bfiz = (const float*)d_in[3];
  const float* kr   = (const float*)d_in[4];
  const float* br   = (const float*)d_in[5];
  const float* wout = (const float*)d_in[6];
  const float* bout = (const float*)d_in[7];
  float* out = (float*)d_out;
  // ws: xw[128 items][2 parities][256 ch] u32 = 256 KB. 0xAA poison -> tag
  // 0xAAAA, never equals a version in [1,2048] -> no init needed.
  unsigned int* xw = (unsigned int*)d_ws;
  lstm_quad<<<dim3(4 * BB), dim3(1024), 0, stream>>>(
      u, x0, kfiz, bfiz, kr, br, wout, bout, out, xw);
}

// Round 7
// 6528.617 us; speedup vs baseline: 3.2066x; 1.1192x over previous
//
#include <hip/hip_runtime.h>
#include <cstdint>
#include <cstddef>

// SingleLayerLSTM: B=128, T=2048, D=64, H=256, O=32.
// v7 = v5 base (residency-safe block mapping p=blk>>2: an item's 4 blocks are
// CONTIGUOUS -> partial residency degrades to serial passes, never deadlock;
// v6's p=blk&127 remap could deadlock under partial residency -> hang) +
// exchange-latency overlap:
//  - Rows split u(64) | own-h(64) | partner-h(192). After publishing h, each
//    thread computes u+own-h part of NEXT step's preactivation (16 fdot2) and
//    y-work in the exchange shadow; only 24 partner fdot2 + reduce remain on
//    the critical path after the poll.
//  - LDS h stored permuted: [own quarter (64) | partner channels in P-order
//    (192)]; W_out staged in the SAME permutation so y-dots stay consistent.
//  - Partner slab stride 12 halfwords = 6 dwords: rq*6 mod 32 all-distinct ->
//    conflict-free b64 broadcasts.
//  - Exchange: xw[item][parity][256] u32 = (ver<<16)|fp16(h); relaxed agent
//    atomics only (no L2-wrecking acquire/release). 0xAA poison tag never
//    matches a version in [1,2048] -> no init. Slot-overwrite skew bounded by
//    the transitive step dependency (producer 2 ahead => consumer consumed).

#define HH 256
#define DD 64
#define TT 2048
#define BB 128
#define OO 32

typedef _Float16 f16x2 __attribute__((ext_vector_type(2)));

__device__ __forceinline__ f16x2 b2h(int v) { return __builtin_bit_cast(f16x2, v); }
__device__ __forceinline__ int h2b(f16x2 v) { return __builtin_bit_cast(int, v); }

#if __has_builtin(__builtin_amdgcn_fdot2)
__device__ __forceinline__ float fdot2(f16x2 a, f16x2 b, float c) {
  return __builtin_amdgcn_fdot2(a, b, c, false);
}
#else
__device__ __forceinline__ float fdot2(f16x2 a, f16x2 b, float c) {
  return fmaf((float)a.y, (float)b.y, fmaf((float)a.x, (float)b.x, c));
}
#endif

__device__ __forceinline__ float frcp(float x) { return __builtin_amdgcn_rcpf(x); }
__device__ __forceinline__ float sigm(float x)  { return frcp(1.0f + __expf(-x)); }
__device__ __forceinline__ float tanhf_(float x){ return 1.0f - 2.0f * frcp(1.0f + __expf(2.0f * x)); }

#if __has_builtin(__builtin_amdgcn_update_dpp)
#define ROR_ADD16(x) do { \
  x += __builtin_bit_cast(float, __builtin_amdgcn_update_dpp(0, __builtin_bit_cast(int, x), 0x121, 0xf, 0xf, true)); \
  x += __builtin_bit_cast(float, __builtin_amdgcn_update_dpp(0, __builtin_bit_cast(int, x), 0x122, 0xf, 0xf, true)); \
  x += __builtin_bit_cast(float, __builtin_amdgcn_update_dpp(0, __builtin_bit_cast(int, x), 0x124, 0xf, 0xf, true)); \
  x += __builtin_bit_cast(float, __builtin_amdgcn_update_dpp(0, __builtin_bit_cast(int, x), 0x128, 0xf, 0xf, true)); \
} while (0)
#else
#define ROR_ADD16(x) do { \
  x += __shfl_xor(x, 1); x += __shfl_xor(x, 2); \
  x += __shfl_xor(x, 4); x += __shfl_xor(x, 8); \
} while (0)
#endif

__global__ __launch_bounds__(1024)
void lstm_quad(const float* __restrict__ u,    const float* __restrict__ x0,
               const float* __restrict__ kfiz, const float* __restrict__ bfiz,
               const float* __restrict__ kr,   const float* __restrict__ br,
               const float* __restrict__ wout, const float* __restrict__ bout,
               float* __restrict__ out, unsigned int* __restrict__ xw)
{
  const int tid = threadIdx.x;
  const int p   = blockIdx.x >> 2;         // item: 4 CONTIGUOUS blocks (safe)
  const int q4  = blockIdx.x & 3;          // quarter
  const int c   = tid >> 4;                // channel within quarter [0,64)
  const int rq  = tid & 15;                // row slice
  const int cg  = q4 * 64 + c;             // global channel [0,256)

  // uh layout (halfwords): [0,64) u | [64,128) own-quarter h | [128,320) partner h
  __shared__ __align__(16) _Float16 uh[2][320];
  __shared__ float yred[2][8][17];
  __shared__ __align__(16) int wopk[16 * 8 * 8];   // W_out pairs, permuted rows

  // ---- register-resident weights (40 pairs) ----
  // u rows rq*4+{0..3}; own-h rows 64+q4*64+rq*4+{0..3}; partner rows
  // 64+P[rq*12+m], P[j] = j<q4*64 ? j : j+64.
  int w2u[8], w2o[8], w2p[24];
#pragma unroll
  for (int g = 0; g < 4; ++g) {
    const float* colp = (g < 3) ? (kfiz + g * HH + cg) : (kr + cg);
    const int cst = (g < 3) ? 3 * HH : HH;
#pragma unroll
    for (int k = 0; k < 2; ++k) {
      f16x2 v;
      v.x = (_Float16)colp[(rq * 4 + 2 * k    ) * cst];
      v.y = (_Float16)colp[(rq * 4 + 2 * k + 1) * cst];
      w2u[g * 2 + k] = h2b(v);
      f16x2 w;
      w.x = (_Float16)colp[(DD + q4 * 64 + rq * 4 + 2 * k    ) * cst];
      w.y = (_Float16)colp[(DD + q4 * 64 + rq * 4 + 2 * k + 1) * cst];
      w2o[g * 2 + k] = h2b(w);
    }
#pragma unroll
    for (int m = 0; m < 6; ++m) {
      const int j0 = rq * 12 + 2 * m, j1 = j0 + 1;
      const int r0 = DD + (j0 < q4 * 64 ? j0 : j0 + 64);
      const int r1 = DD + (j1 < q4 * 64 ? j1 : j1 + 64);
      f16x2 v;
      v.x = (_Float16)colp[r0 * cst];
      v.y = (_Float16)colp[r1 * cst];
      w2p[g * 6 + m] = h2b(v);
    }
  }
  const float bf_ = bfiz[0 * HH + cg];
  const float bi_ = bfiz[1 * HH + cg];
  const float bz_ = bfiz[2 * HH + cg];
  const float br_ = br[cg];

  // ---- W_out staged permuted: LDS h-position pos -> global channel ----
  {
    const int jc = tid >> 6, o = (tid >> 3) & 7, k = tid & 7;   // covers 1024
    const int pos0 = jc * 16 + 2 * k, pos1 = pos0 + 1;
    const int ch0 = (pos0 < 64) ? q4 * 64 + pos0
                                : ((pos0 - 64) < q4 * 64 ? pos0 - 64 : pos0);
    const int ch1 = (pos1 < 64) ? q4 * 64 + pos1
                                : ((pos1 - 64) < q4 * 64 ? pos1 - 64 : pos1);
    f16x2 v;
    v.x = (_Float16)wout[ch0 * OO + q4 * 8 + o];
    v.y = (_Float16)wout[ch1 * OO + q4 * 8 + o];
    wopk[tid] = h2b(v);
  }
  const float bo = (tid >= 384 && tid < 392) ? bout[q4 * 8 + (tid - 384)] : 0.0f;

  // ---- state init ----
  float cs = x0[p * 2 * HH + HH + cg];
  if (tid < HH) {   // h0 into permuted position
    const int pos = (tid >= q4 * 64 && tid < q4 * 64 + 64)
                        ? 64 + (tid - q4 * 64)
                        : 128 + (tid < q4 * 64 ? tid : tid - 64);
    uh[0][pos] = (_Float16)x0[p * 2 * HH + tid];
  }
  if (tid >= 256 && tid < 256 + DD)
    uh[0][tid - 256] = (_Float16)u[((size_t)p * TT) * DD + (tid - 256)];

  unsigned int* xwp = xw + (size_t)p * 2 * 256;
  const int chp = (tid < q4 * 64) ? tid : tid + 64;   // poll map (tid<192)

  __syncthreads();

  // ---- prime: u+own-h partial for step 0 ----
  float af, ai, az, ar;
  {
    const int2 uv = *(const int2*)&uh[0][rq * 4];
    const int2 ov = *(const int2*)&uh[0][64 + rq * 4];
    f16x2 u0 = b2h(uv.x), u1 = b2h(uv.y), o0 = b2h(ov.x), o1 = b2h(ov.y);
    af = fdot2(b2h(w2u[0]), u0, 0.0f); af = fdot2(b2h(w2u[1]), u1, af);
    af = fdot2(b2h(w2o[0]), o0, af);   af = fdot2(b2h(w2o[1]), o1, af);
    ai = fdot2(b2h(w2u[2]), u0, 0.0f); ai = fdot2(b2h(w2u[3]), u1, ai);
    ai = fdot2(b2h(w2o[2]), o0, ai);   ai = fdot2(b2h(w2o[3]), o1, ai);
    az = fdot2(b2h(w2u[4]), u0, 0.0f); az = fdot2(b2h(w2u[5]), u1, az);
    az = fdot2(b2h(w2o[4]), o0, az);   az = fdot2(b2h(w2o[5]), o1, az);
    ar = fdot2(b2h(w2u[6]), u0, 0.0f); ar = fdot2(b2h(w2u[7]), u1, ar);
    ar = fdot2(b2h(w2o[6]), o0, ar);   ar = fdot2(b2h(w2o[7]), o1, ar);
  }

  for (int s = 0; s < TT; ++s) {
    const int cur = s & 1;
    const int nxt = cur ^ 1;

    float unext = 0.0f;
    if (tid >= 1024 - DD && s + 1 < TT)
      unext = u[((size_t)p * TT + s + 1) * DD + (tid - (1024 - DD))];

    // ---- A: partner part (critical path), 24 fdot2 ----
    {
      const int2* pp = (const int2*)&uh[cur][128 + rq * 12];
      int2 v0 = pp[0], v1 = pp[1], v2 = pp[2];
      f16x2 h0 = b2h(v0.x), h1 = b2h(v0.y), h2 = b2h(v1.x),
            h3 = b2h(v1.y), h4 = b2h(v2.x), h5 = b2h(v2.y);
      af = fdot2(b2h(w2p[ 0]), h0, af); af = fdot2(b2h(w2p[ 1]), h1, af);
      af = fdot2(b2h(w2p[ 2]), h2, af); af = fdot2(b2h(w2p[ 3]), h3, af);
      af = fdot2(b2h(w2p[ 4]), h4, af); af = fdot2(b2h(w2p[ 5]), h5, af);
      ai = fdot2(b2h(w2p[ 6]), h0, ai); ai = fdot2(b2h(w2p[ 7]), h1, ai);
      ai = fdot2(b2h(w2p[ 8]), h2, ai); ai = fdot2(b2h(w2p[ 9]), h3, ai);
      ai = fdot2(b2h(w2p[10]), h4, ai); ai = fdot2(b2h(w2p[11]), h5, ai);
      az = fdot2(b2h(w2p[12]), h0, az); az = fdot2(b2h(w2p[13]), h1, az);
      az = fdot2(b2h(w2p[14]), h2, az); az = fdot2(b2h(w2p[15]), h3, az);
      az = fdot2(b2h(w2p[16]), h4, az); az = fdot2(b2h(w2p[17]), h5, az);
      ar = fdot2(b2h(w2p[18]), h0, ar); ar = fdot2(b2h(w2p[19]), h1, ar);
      ar = fdot2(b2h(w2p[20]), h2, ar); ar = fdot2(b2h(w2p[21]), h3, ar);
      ar = fdot2(b2h(w2p[22]), h4, ar); ar = fdot2(b2h(w2p[23]), h5, ar);
    }

    // ---- B: reduce + activations ----
    ROR_ADD16(af); ROR_ADD16(ai); ROR_ADD16(az); ROR_ADD16(ar);
    const float f = sigm(af + bf_), i = sigm(ai + bi_);
    const float z = sigm(az + bz_), r = tanhf_(ar + br_);
    cs = f * cs + i * r;
    const float hn = z * tanhf_(cs);

    // ---- C: publish own channel + u_{s+1} store ----
    if (rq == 0) {
      const unsigned int hb16 =
          (unsigned int)__builtin_bit_cast(unsigned short, (_Float16)hn);
      __hip_atomic_store(&xwp[nxt * 256 + cg],
                         ((unsigned int)(s + 1) << 16) | hb16,
                         __ATOMIC_RELAXED, __HIP_MEMORY_SCOPE_AGENT);
      uh[nxt][64 + c] = (_Float16)hn;
    }
    if (tid >= 1024 - DD && s + 1 < TT)
      uh[nxt][tid - (1024 - DD)] = (_Float16)unext;
    __syncthreads();   // B1: own h + u_{s+1} in uh[nxt]

    // ---- D: shadow work while partner h propagates through L3 ----
    if (s >= 2 && tid >= 384 && tid < 392) {          // y store for s-2
      const int o = tid - 384;
      float ssum = bo;
#pragma unroll
      for (int k = 0; k < 16; ++k) ssum += yred[nxt][o][k];
      out[((size_t)p * TT + (s - 2)) * OO + q4 * 8 + o] = ssum;
    }
    if (s >= 1 && tid >= 256 && tid < 384) {          // y partials for s-1
      const int idx = tid - 256, o = idx & 7, jc = idx >> 3;
      const int2* hq = (const int2*)&uh[cur][64 + jc * 16];
      int2 h0 = hq[0], h1 = hq[1], h2 = hq[2], h3 = hq[3];
      const int4* wp = (const int4*)&wopk[(jc * 8 + o) * 8];
      int4 wa = wp[0], wb = wp[1];
      float ya = 0.0f;
      ya = fdot2(b2h(wa.x), b2h(h0.x), ya);
      ya = fdot2(b2h(wa.y), b2h(h0.y), ya);
      ya = fdot2(b2h(wa.z), b2h(h1.x), ya);
      ya = fdot2(b2h(wa.w), b2h(h1.y), ya);
      ya = fdot2(b2h(wb.x), b2h(h2.x), ya);
      ya = fdot2(b2h(wb.y), b2h(h2.y), ya);
      ya = fdot2(b2h(wb.z), b2h(h3.x), ya);
      ya = fdot2(b2h(wb.w), b2h(h3.y), ya);
      yred[cur][o][jc] = ya;
    }
    if (s + 1 < TT) {                                  // u+own-h partial, s+1
      const int2 uv = *(const int2*)&uh[nxt][rq * 4];
      const int2 ov = *(const int2*)&uh[nxt][64 + rq * 4];
      f16x2 u0 = b2h(uv.x), u1 = b2h(uv.y), o0 = b2h(ov.x), o1 = b2h(ov.y);
      af = fdot2(b2h(w2u[0]), u0, 0.0f); af = fdot2(b2h(w2u[1]), u1, af);
      af = fdot2(b2h(w2o[0]), o0, af);   af = fdot2(b2h(w2o[1]), o1, af);
      ai = fdot2(b2h(w2u[2]), u0, 0.0f); ai = fdot2(b2h(w2u[3]), u1, ai);
      ai = fdot2(b2h(w2o[2]), o0, ai);   ai = fdot2(b2h(w2o[3]), o1, ai);
      az = fdot2(b2h(w2u[4]), u0, 0.0f); az = fdot2(b2h(w2u[5]), u1, az);
      az = fdot2(b2h(w2o[4]), o0, az);   az = fdot2(b2h(w2o[5]), o1, az);
      ar = fdot2(b2h(w2u[6]), u0, 0.0f); ar = fdot2(b2h(w2u[7]), u1, ar);
      ar = fdot2(b2h(w2o[6]), o0, ar);   ar = fdot2(b2h(w2o[7]), o1, ar);
    }

    // ---- E: poll partner channels (lanes 0..191) ----
    if (tid < 192) {
      const unsigned int want = (unsigned int)(s + 1) << 16;
      unsigned int v;
      do {
        v = __hip_atomic_load(&xwp[nxt * 256 + chp],
                              __ATOMIC_RELAXED, __HIP_MEMORY_SCOPE_AGENT);
      } while ((v & 0xffff0000u) != want);
      uh[nxt][128 + tid] =
          __builtin_bit_cast(_Float16, (unsigned short)(v & 0xffffu));
    }
    __syncthreads();   // B2: uh[nxt] fully assembled
  }

  // ---- epilogue: y_{TT-2} from yred[1], y_{TT-1} from uh[0] ----
  if (tid >= 384 && tid < 392) {
    const int o = tid - 384;
    float ssum = bo;
#pragma unroll
    for (int k = 0; k < 16; ++k) ssum += yred[1][o][k];
    out[((size_t)p * TT + (TT - 2)) * OO + q4 * 8 + o] = ssum;
  }
  if (tid >= 256 && tid < 384) {
    const int idx = tid - 256, o = idx & 7, jc = idx >> 3;
    const int2* hq = (const int2*)&uh[0][64 + jc * 16];
    int2 h0 = hq[0], h1 = hq[1], h2 = hq[2], h3 = hq[3];
    const int4* wp = (const int4*)&wopk[(jc * 8 + o) * 8];
    int4 wa = wp[0], wb = wp[1];
    float ya = 0.0f;
    ya = fdot2(b2h(wa.x), b2h(h0.x), ya);
    ya = fdot2(b2h(wa.y), b2h(h0.y), ya);
    ya = fdot2(b2h(wa.z), b2h(h1.x), ya);
    ya = fdot2(b2h(wa.w), b2h(h1.y), ya);
    ya = fdot2(b2h(wb.x), b2h(h2.x), ya);
    ya = fdot2(b2h(wb.y), b2h(h2.y), ya);
    ya = fdot2(b2h(wb.z), b2h(h3.x), ya);
    ya = fdot2(b2h(wb.w), b2h(h3.y), ya);
    yred[0][o][jc] = ya;
  }
  __syncthreads();
  if (tid >= 384 && tid < 392) {
    const int o = tid - 384;
    float ssum = bo;
#pragma unroll
    for (int k = 0; k < 16; ++k) ssum += yred[0][o][k];
    out[((size_t)p * TT + (TT - 1)) * OO + q4 * 8 + o] = ssum;
  }
}

extern "C" void kernel_launch(void* const* d_in, const int* in_sizes, int n_in,
                              void* d_out, int out_size, void* d_ws, size_t ws_size,
                              hipStream_t stream) {
  const float* u    = (const float*)d_in[0];
  const float* x0   = (const float*)d_in[1];
  const float* kfiz = (const float*)d_in[2];
  const float* bfiz = (const float*)d_in[3];
  const float* kr   = (const float*)d_in[4];
  const float* br   = (const float*)d_in[5];
  const float* wout = (const float*)d_in[6];
  const float* bout = (const float*)d_in[7];
  float* out = (float*)d_out;
  unsigned int* xw = (unsigned int*)d_ws;   // 256 KB; poison tag 0xAAAA safe
  lstm_quad<<<dim3(4 * BB), dim3(1024), 0, stream>>>(
      u, x0, kfiz, bfiz, kr, br, wout, bout, out, xw);
}

// Round 8
// 5874.050 us; speedup vs baseline: 3.5639x; 1.1114x over previous
//
#include <hip/hip_runtime.h>
#include <cstdint>
#include <cstddef>

// SingleLayerLSTM: B=128, T=2048, D=64, H=256, O=32.
// v8 = v7 structure at 512 threads/block with the 128-VGPR cap that v1
// empirically proved for (512,2) launch bounds. Rationale (R7 counters):
// VALU-busy 4100 cyc/step is ~2.6x the hand-counted instr stream, and all
// non-dot overhead (redundant act, reduce, addressing, barrier convoy) is
// per-WAVE. Halving waves (16->8 per block) conserves dot work (80 fdot2 per
// thread instead of 40) and halves the per-wave overhead + barrier convoy.
//  - 512 blocks x 512 thr; item p = blk>>2 (CONTIGUOUS -> residency-safe),
//    quarter q4 = blk&3. 2 blocks/CU, 4 waves/SIMD x 128 VGPR = exact fit.
//  - Thread (c = tid>>3 in [0,64), rq = tid&7): all 4 gates of channel
//    q4*64+c; rows split u(8)/own-h(8)/partner-h(24) per slice ->
//    w2u[16]+w2o[16]+w2p[48] = 80 fp16-pair VGPRs.
//  - u+own-h of step s+1 computed in the exchange shadow (32 fdot2);
//    critical path after poll = 48 partner fdot2 + reduce + act.
//  - Reduce over 8 slices: shfl_xor 1/2/4 (ds_swizzle, LDS pipe).
//  - LDS uh[2][320] hw: [u 64 | own 64 | partner 192 (P-order)]; partner b128
//    reads: dword offset 64+12*rq -> banks 12rq mod 32 all-distinct, and
//    broadcast across channels -> conflict-free.
//  - Exchange: xw[item][parity][256] u32 = (ver<<16)|fp16(h), relaxed agent
//    atomics only; poison tag 0xAAAA never matches -> no init, replay-safe.

#define HH 256
#define DD 64
#define TT 2048
#define BB 128
#define OO 32

typedef _Float16 f16x2 __attribute__((ext_vector_type(2)));

__device__ __forceinline__ f16x2 b2h(int v) { return __builtin_bit_cast(f16x2, v); }
__device__ __forceinline__ int h2b(f16x2 v) { return __builtin_bit_cast(int, v); }

#if __has_builtin(__builtin_amdgcn_fdot2)
__device__ __forceinline__ float fdot2(f16x2 a, f16x2 b, float c) {
  return __builtin_amdgcn_fdot2(a, b, c, false);
}
#else
__device__ __forceinline__ float fdot2(f16x2 a, f16x2 b, float c) {
  return fmaf((float)a.y, (float)b.y, fmaf((float)a.x, (float)b.x, c));
}
#endif

__device__ __forceinline__ float frcp(float x) { return __builtin_amdgcn_rcpf(x); }
__device__ __forceinline__ float sigm(float x)  { return frcp(1.0f + __expf(-x)); }
__device__ __forceinline__ float tanhf_(float x){ return 1.0f - 2.0f * frcp(1.0f + __expf(2.0f * x)); }

#define XOR_ADD8(x) do { \
  x += __shfl_xor(x, 1); x += __shfl_xor(x, 2); x += __shfl_xor(x, 4); \
} while (0)

__global__ __launch_bounds__(512, 2)
void lstm_quad(const float* __restrict__ u,    const float* __restrict__ x0,
               const float* __restrict__ kfiz, const float* __restrict__ bfiz,
               const float* __restrict__ kr,   const float* __restrict__ br,
               const float* __restrict__ wout, const float* __restrict__ bout,
               float* __restrict__ out, unsigned int* __restrict__ xw)
{
  const int tid = threadIdx.x;
  const int p   = blockIdx.x >> 2;         // item: 4 CONTIGUOUS blocks (safe)
  const int q4  = blockIdx.x & 3;          // quarter
  const int c   = tid >> 3;                // channel within quarter [0,64)
  const int rq  = tid & 7;                 // row slice
  const int cg  = q4 * 64 + c;             // global channel [0,256)

  // uh layout (halfwords): [0,64) u | [64,128) own-quarter h | [128,320) partner h
  __shared__ __align__(16) _Float16 uh[2][320];
  __shared__ float yred[2][8][17];
  __shared__ __align__(16) int wopk[16 * 8 * 8];   // W_out pairs, permuted rows

  // ---- register-resident weights (80 pairs) ----
  int w2u[16], w2o[16], w2p[48];
#pragma unroll
  for (int g = 0; g < 4; ++g) {
    const float* colp = (g < 3) ? (kfiz + g * HH + cg) : (kr + cg);
    const int cst = (g < 3) ? 3 * HH : HH;
#pragma unroll
    for (int k = 0; k < 4; ++k) {
      f16x2 v;
      v.x = (_Float16)colp[(rq * 8 + 2 * k    ) * cst];
      v.y = (_Float16)colp[(rq * 8 + 2 * k + 1) * cst];
      w2u[g * 4 + k] = h2b(v);
      f16x2 w;
      w.x = (_Float16)colp[(DD + q4 * 64 + rq * 8 + 2 * k    ) * cst];
      w.y = (_Float16)colp[(DD + q4 * 64 + rq * 8 + 2 * k + 1) * cst];
      w2o[g * 4 + k] = h2b(w);
    }
#pragma unroll
    for (int m = 0; m < 12; ++m) {
      const int j0 = rq * 24 + 2 * m, j1 = j0 + 1;
      const int r0 = DD + (j0 < q4 * 64 ? j0 : j0 + 64);
      const int r1 = DD + (j1 < q4 * 64 ? j1 : j1 + 64);
      f16x2 v;
      v.x = (_Float16)colp[r0 * cst];
      v.y = (_Float16)colp[r1 * cst];
      w2p[g * 12 + m] = h2b(v);
    }
  }
  const float bf_ = bfiz[0 * HH + cg];
  const float bi_ = bfiz[1 * HH + cg];
  const float bz_ = bfiz[2 * HH + cg];
  const float br_ = br[cg];

  // ---- W_out staged permuted: LDS h-position pos -> global channel ----
  for (int t = tid; t < 1024; t += 512) {
    const int jc = t >> 6, o = (t >> 3) & 7, k = t & 7;
    const int pos0 = jc * 16 + 2 * k, pos1 = pos0 + 1;
    const int ch0 = (pos0 < 64) ? q4 * 64 + pos0
                                : ((pos0 - 64) < q4 * 64 ? pos0 - 64 : pos0);
    const int ch1 = (pos1 < 64) ? q4 * 64 + pos1
                                : ((pos1 - 64) < q4 * 64 ? pos1 - 64 : pos1);
    f16x2 v;
    v.x = (_Float16)wout[ch0 * OO + q4 * 8 + o];
    v.y = (_Float16)wout[ch1 * OO + q4 * 8 + o];
    wopk[t] = h2b(v);
  }
  const float bo = (tid >= 384 && tid < 392) ? bout[q4 * 8 + (tid - 384)] : 0.0f;

  // ---- state init ----
  float cs = x0[p * 2 * HH + HH + cg];
  if (tid < HH) {   // h0 into permuted position
    const int pos = (tid >= q4 * 64 && tid < q4 * 64 + 64)
                        ? 64 + (tid - q4 * 64)
                        : 128 + (tid < q4 * 64 ? tid : tid - 64);
    uh[0][pos] = (_Float16)x0[p * 2 * HH + tid];
  }
  if (tid >= 256 && tid < 256 + DD)
    uh[0][tid - 256] = (_Float16)u[((size_t)p * TT) * DD + (tid - 256)];

  unsigned int* xwp = xw + (size_t)p * 2 * 256;
  const int chp = (tid < q4 * 64) ? tid : tid + 64;   // poll map (tid<192)

  __syncthreads();

  // ---- prime: u+own-h partial for step 0 (32 fdot2) ----
  float af, ai, az, ar;
  {
    const int4 uv = *(const int4*)&uh[0][rq * 8];
    const int4 ov = *(const int4*)&uh[0][64 + rq * 8];
    f16x2 u0 = b2h(uv.x), u1 = b2h(uv.y), u2 = b2h(uv.z), u3 = b2h(uv.w);
    f16x2 o0 = b2h(ov.x), o1 = b2h(ov.y), o2 = b2h(ov.z), o3 = b2h(ov.w);
    af = fdot2(b2h(w2u[ 0]), u0, 0.0f); af = fdot2(b2h(w2u[ 1]), u1, af);
    af = fdot2(b2h(w2u[ 2]), u2, af);   af = fdot2(b2h(w2u[ 3]), u3, af);
    af = fdot2(b2h(w2o[ 0]), o0, af);   af = fdot2(b2h(w2o[ 1]), o1, af);
    af = fdot2(b2h(w2o[ 2]), o2, af);   af = fdot2(b2h(w2o[ 3]), o3, af);
    ai = fdot2(b2h(w2u[ 4]), u0, 0.0f); ai = fdot2(b2h(w2u[ 5]), u1, ai);
    ai = fdot2(b2h(w2u[ 6]), u2, ai);   ai = fdot2(b2h(w2u[ 7]), u3, ai);
    ai = fdot2(b2h(w2o[ 4]), o0, ai);   ai = fdot2(b2h(w2o[ 5]), o1, ai);
    ai = fdot2(b2h(w2o[ 6]), o2, ai);   ai = fdot2(b2h(w2o[ 7]), o3, ai);
    az = fdot2(b2h(w2u[ 8]), u0, 0.0f); az = fdot2(b2h(w2u[ 9]), u1, az);
    az = fdot2(b2h(w2u[10]), u2, az);   az = fdot2(b2h(w2u[11]), u3, az);
    az = fdot2(b2h(w2o[ 8]), o0, az);   az = fdot2(b2h(w2o[ 9]), o1, az);
    az = fdot2(b2h(w2o[10]), o2, az);   az = fdot2(b2h(w2o[11]), o3, az);
    ar = fdot2(b2h(w2u[12]), u0, 0.0f); ar = fdot2(b2h(w2u[13]), u1, ar);
    ar = fdot2(b2h(w2u[14]), u2, ar);   ar = fdot2(b2h(w2u[15]), u3, ar);
    ar = fdot2(b2h(w2o[12]), o0, ar);   ar = fdot2(b2h(w2o[13]), o1, ar);
    ar = fdot2(b2h(w2o[14]), o2, ar);   ar = fdot2(b2h(w2o[15]), o3, ar);
  }

  for (int s = 0; s < TT; ++s) {
    const int cur = s & 1;
    const int nxt = cur ^ 1;

    float unext = 0.0f;
    if (tid >= 512 - DD && s + 1 < TT)
      unext = u[((size_t)p * TT + s + 1) * DD + (tid - (512 - DD))];

    // ---- A: partner part (critical path), 48 fdot2 over 24 rows ----
    {
      const int4* pp = (const int4*)&uh[cur][128 + rq * 24];
      int4 v0 = pp[0], v1 = pp[1], v2 = pp[2];
      f16x2 h0 = b2h(v0.x), h1 = b2h(v0.y), h2  = b2h(v0.z), h3  = b2h(v0.w);
      f16x2 h4 = b2h(v1.x), h5 = b2h(v1.y), h6  = b2h(v1.z), h7  = b2h(v1.w);
      f16x2 h8 = b2h(v2.x), h9 = b2h(v2.y), h10 = b2h(v2.z), h11 = b2h(v2.w);
#define GDOT(acc, base) do { \
      acc = fdot2(b2h(w2p[(base) +  0]), h0,  acc); \
      acc = fdot2(b2h(w2p[(base) +  1]), h1,  acc); \
      acc = fdot2(b2h(w2p[(base) +  2]), h2,  acc); \
      acc = fdot2(b2h(w2p[(base) +  3]), h3,  acc); \
      acc = fdot2(b2h(w2p[(base) +  4]), h4,  acc); \
      acc = fdot2(b2h(w2p[(base) +  5]), h5,  acc); \
      acc = fdot2(b2h(w2p[(base) +  6]), h6,  acc); \
      acc = fdot2(b2h(w2p[(base) +  7]), h7,  acc); \
      acc = fdot2(b2h(w2p[(base) +  8]), h8,  acc); \
      acc = fdot2(b2h(w2p[(base) +  9]), h9,  acc); \
      acc = fdot2(b2h(w2p[(base) + 10]), h10, acc); \
      acc = fdot2(b2h(w2p[(base) + 11]), h11, acc); \
    } while (0)
      GDOT(af, 0); GDOT(ai, 12); GDOT(az, 24); GDOT(ar, 36);
#undef GDOT
    }

    // ---- B: reduce over 8 slices + activations ----
    XOR_ADD8(af); XOR_ADD8(ai); XOR_ADD8(az); XOR_ADD8(ar);
    const float f = sigm(af + bf_), i = sigm(ai + bi_);
    const float z = sigm(az + bz_), r = tanhf_(ar + br_);
    cs = f * cs + i * r;
    const float hn = z * tanhf_(cs);

    // ---- C: publish own channel + u_{s+1} store ----
    if (rq == 0) {
      const unsigned int hb16 =
          (unsigned int)__builtin_bit_cast(unsigned short, (_Float16)hn);
      __hip_atomic_store(&xwp[nxt * 256 + cg],
                         ((unsigned int)(s + 1) << 16) | hb16,
                         __ATOMIC_RELAXED, __HIP_MEMORY_SCOPE_AGENT);
      uh[nxt][64 + c] = (_Float16)hn;
    }
    if (tid >= 512 - DD && s + 1 < TT)
      uh[nxt][tid - (512 - DD)] = (_Float16)unext;
    __syncthreads();   // B1: own h + u_{s+1} in uh[nxt]

    // ---- D: shadow work while partner h propagates through L3 ----
    if (s >= 2 && tid >= 384 && tid < 392) {          // y store for s-2
      const int o = tid - 384;
      float ssum = bo;
#pragma unroll
      for (int k = 0; k < 16; ++k) ssum += yred[nxt][o][k];
      out[((size_t)p * TT + (s - 2)) * OO + q4 * 8 + o] = ssum;
    }
    if (s >= 1 && tid >= 256 && tid < 384) {          // y partials for s-1
      const int idx = tid - 256, o = idx & 7, jc = idx >> 3;
      const int2* hq = (const int2*)&uh[cur][64 + jc * 16];
      int2 h0 = hq[0], h1 = hq[1], h2 = hq[2], h3 = hq[3];
      const int4* wp = (const int4*)&wopk[(jc * 8 + o) * 8];
      int4 wa = wp[0], wb = wp[1];
      float ya = 0.0f;
      ya = fdot2(b2h(wa.x), b2h(h0.x), ya);
      ya = fdot2(b2h(wa.y), b2h(h0.y), ya);
      ya = fdot2(b2h(wa.z), b2h(h1.x), ya);
      ya = fdot2(b2h(wa.w), b2h(h1.y), ya);
      ya = fdot2(b2h(wb.x), b2h(h2.x), ya);
      ya = fdot2(b2h(wb.y), b2h(h2.y), ya);
      ya = fdot2(b2h(wb.z), b2h(h3.x), ya);
      ya = fdot2(b2h(wb.w), b2h(h3.y), ya);
      yred[cur][o][jc] = ya;
    }
    if (s + 1 < TT) {                                  // u+own-h partial, s+1
      const int4 uv = *(const int4*)&uh[nxt][rq * 8];
      const int4 ov = *(const int4*)&uh[nxt][64 + rq * 8];
      f16x2 u0 = b2h(uv.x), u1 = b2h(uv.y), u2 = b2h(uv.z), u3 = b2h(uv.w);
      f16x2 o0 = b2h(ov.x), o1 = b2h(ov.y), o2 = b2h(ov.z), o3 = b2h(ov.w);
      af = fdot2(b2h(w2u[ 0]), u0, 0.0f); af = fdot2(b2h(w2u[ 1]), u1, af);
      af = fdot2(b2h(w2u[ 2]), u2, af);   af = fdot2(b2h(w2u[ 3]), u3, af);
      af = fdot2(b2h(w2o[ 0]), o0, af);   af = fdot2(b2h(w2o[ 1]), o1, af);
      af = fdot2(b2h(w2o[ 2]), o2, af);   af = fdot2(b2h(w2o[ 3]), o3, af);
      ai = fdot2(b2h(w2u[ 4]), u0, 0.0f); ai = fdot2(b2h(w2u[ 5]), u1, ai);
      ai = fdot2(b2h(w2u[ 6]), u2, ai);   ai = fdot2(b2h(w2u[ 7]), u3, ai);
      ai = fdot2(b2h(w2o[ 4]), o0, ai);   ai = fdot2(b2h(w2o[ 5]), o1, ai);
      ai = fdot2(b2h(w2o[ 6]), o2, ai);   ai = fdot2(b2h(w2o[ 7]), o3, ai);
      az = fdot2(b2h(w2u[ 8]), u0, 0.0f); az = fdot2(b2h(w2u[ 9]), u1, az);
      az = fdot2(b2h(w2u[10]), u2, az);   az = fdot2(b2h(w2u[11]), u3, az);
      az = fdot2(b2h(w2o[ 8]), o0, az);   az = fdot2(b2h(w2o[ 9]), o1, az);
      az = fdot2(b2h(w2o[10]), o2, az);   az = fdot2(b2h(w2o[11]), o3, az);
      ar = fdot2(b2h(w2u[12]), u0, 0.0f); ar = fdot2(b2h(w2u[13]), u1, ar);
      ar = fdot2(b2h(w2u[14]), u2, ar);   ar = fdot2(b2h(w2u[15]), u3, ar);
      ar = fdot2(b2h(w2o[12]), o0, ar);   ar = fdot2(b2h(w2o[13]), o1, ar);
      ar = fdot2(b2h(w2o[14]), o2, ar);   ar = fdot2(b2h(w2o[15]), o3, ar);
    }

    // ---- E: poll partner channels (lanes 0..191) ----
    if (tid < 192) {
      const unsigned int want = (unsigned int)(s + 1) << 16;
      unsigned int v;
      do {
        v = __hip_atomic_load(&xwp[nxt * 256 + chp],
                              __ATOMIC_RELAXED, __HIP_MEMORY_SCOPE_AGENT);
      } while ((v & 0xffff0000u) != want);
      uh[nxt][128 + tid] =
          __builtin_bit_cast(_Float16, (unsigned short)(v & 0xffffu));
    }
    __syncthreads();   // B2: uh[nxt] fully assembled
  }

  // ---- epilogue: y_{TT-2} from yred[1], y_{TT-1} from uh[0] ----
  if (tid >= 384 && tid < 392) {
    const int o = tid - 384;
    float ssum = bo;
#pragma unroll
    for (int k = 0; k < 16; ++k) ssum += yred[1][o][k];
    out[((size_t)p * TT + (TT - 2)) * OO + q4 * 8 + o] = ssum;
  }
  if (tid >= 256 && tid < 384) {
    const int idx = tid - 256, o = idx & 7, jc = idx >> 3;
    const int2* hq = (const int2*)&uh[0][64 + jc * 16];
    int2 h0 = hq[0], h1 = hq[1], h2 = hq[2], h3 = hq[3];
    const int4* wp = (const int4*)&wopk[(jc * 8 + o) * 8];
    int4 wa = wp[0], wb = wp[1];
    float ya = 0.0f;
    ya = fdot2(b2h(wa.x), b2h(h0.x), ya);
    ya = fdot2(b2h(wa.y), b2h(h0.y), ya);
    ya = fdot2(b2h(wa.z), b2h(h1.x), ya);
    ya = fdot2(b2h(wa.w), b2h(h1.y), ya);
    ya = fdot2(b2h(wb.x), b2h(h2.x), ya);
    ya = fdot2(b2h(wb.y), b2h(h2.y), ya);
    ya = fdot2(b2h(wb.z), b2h(h3.x), ya);
    ya = fdot2(b2h(wb.w), b2h(h3.y), ya);
    yred[0][o][jc] = ya;
  }
  __syncthreads();
  if (tid >= 384 && tid < 392) {
    const int o = tid - 384;
    float ssum = bo;
#pragma unroll
    for (int k = 0; k < 16; ++k) ssum += yred[0][o][k];
    out[((size_t)p * TT + (TT - 1)) * OO + q4 * 8 + o] = ssum;
  }
}

extern "C" void kernel_launch(void* const* d_in, const int* in_sizes, int n_in,
                              void* d_out, int out_size, void* d_ws, size_t ws_size,
                              hipStream_t stream) {
  const float* u    = (const float*)d_in[0];
  const float* x0   = (const float*)d_in[1];
  const float* kfiz = (const float*)d_in[2];
  const float* bfiz = (const float*)d_in[3];
  const float* kr   = (const float*)d_in[4];
  const float* br   = (const float*)d_in[5];
  const float* wout = (const float*)d_in[6];
  const float* bout = (const float*)d_in[7];
  float* out = (float*)d_out;
  unsigned int* xw = (unsigned int*)d_ws;   // 256 KB; poison tag 0xAAAA safe
  lstm_quad<<<dim3(4 * BB), dim3(512), 0, stream>>>(
      u, x0, kfiz, bfiz, kr, br, wout, bout, out, xw);
}